// Round 3
// baseline (224.246 us; speedup 1.0000x reference)
//
#include <hip/hip_runtime.h>
#include <hip/hip_cooperative_groups.h>
#include <math.h>

#define SEQ 8192
#define HID 2048
#define NBLK 512
#define NTHR 256
#define NCHUNK 64   // v row-chunks (32 rows each)

namespace cg = cooperative_groups;

// ---------------------------------------------------------------------------
// Fused cooperative kernel.
// Workspace (floats):
//   m     [0,     2048)           : W_pq @ pool + b_pq
//   g     [2048,  4096)           : m * v,  v = hidden @ W_qh
//   energ [4096, 12288)           : enc @ g
//   vpart [12288, 12288+64*2048)  : per-row-chunk partials of v (512 KB)
// ---------------------------------------------------------------------------
__global__ __launch_bounds__(NTHR, 2) void k_fused(
    const float* __restrict__ hidden,
    const float* __restrict__ enc,
    const float* __restrict__ pool,
    const float* __restrict__ W_pq,
    const float* __restrict__ b_pq,
    const float* __restrict__ W_qh,
    float* __restrict__ out,
    float* __restrict__ ws) {

  cg::grid_group grid = cg::this_grid();

  float* m     = ws;
  float* g     = ws + HID;
  float* energ = ws + 2 * HID;
  float* vpart = ws + 2 * HID + SEQ;

  const int tid  = threadIdx.x;
  const int wave = tid >> 6;
  const int lane = tid & 63;
  const int bid  = blockIdx.x;

  __shared__ float4 part[128];  // phase-1 v pair-reduce
  __shared__ float  red[8];     // phase-4 block reduce

  // ---------- Phase 1: m rows + v partials (32 MiB HBM, 64 KB/block) --------
  if (bid < 256) {
    // m[row] = W_pq[row,:] . pool + b_pq[row] — 8 rows/block, 2 per wave
    const float4* p4 = reinterpret_cast<const float4*>(pool);
    #pragma unroll
    for (int rr = 0; rr < 2; ++rr) {
      const int row = bid * 8 + wave * 2 + rr;
      const float4* Wrow = reinterpret_cast<const float4*>(W_pq + (size_t)row * HID);
      float acc = 0.f;
      #pragma unroll
      for (int i = lane; i < HID / 4; i += 64) {
        float4 w = Wrow[i], p = p4[i];
        acc += w.x * p.x + w.y * p.y + w.z * p.z + w.w * p.w;
      }
      #pragma unroll
      for (int off = 32; off; off >>= 1) acc += __shfl_down(acc, off, 64);
      if (lane == 0) m[row] = acc + b_pq[row];
    }
  } else {
    // v partials: unit u = (row-chunk rc of 32 rows) x (col-tile ct of 512)
    const int u  = bid - 256;          // 0..255
    const int ct = u & 3;              // 4 col-tiles x 512 cols
    const int rc = u >> 2;             // 0..63 row-chunks
    const int cq = ct * 128 + (tid & 127);      // float4 column index
    const int r0 = rc * 32 + (tid >> 7) * 16;   // half-chunk per thread group
    float4 acc = {0.f, 0.f, 0.f, 0.f};
    #pragma unroll
    for (int i = 0; i < 16; ++i) {
      const int r = r0 + i;
      const float h  = hidden[r];
      const float4 w = reinterpret_cast<const float4*>(W_qh + (size_t)r * HID)[cq];
      acc.x += h * w.x; acc.y += h * w.y; acc.z += h * w.z; acc.w += h * w.w;
    }
    if (tid >= 128) part[tid - 128] = acc;
    __syncthreads();
    if (tid < 128) {
      float4 b2 = part[tid];
      acc.x += b2.x; acc.y += b2.y; acc.z += b2.z; acc.w += b2.w;
      reinterpret_cast<float4*>(vpart)[rc * (HID / 4) + cq] = acc;
    }
  }

  grid.sync();

  // ---------- Phase 2: v = sum(vpart) over 64 chunks, g = m*v (L2) ----------
  if (bid < 32) {
    const int ql   = tid >> 4;          // 16 quads per block
    const int s    = tid & 15;          // 16 threads per quad
    const int quad = bid * 16 + ql;     // float4 column index, < 512
    float4 acc = {0.f, 0.f, 0.f, 0.f};
    #pragma unroll
    for (int i = 0; i < 4; ++i) {
      const int chunk = s * 4 + i;
      float4 p = reinterpret_cast<const float4*>(vpart)[chunk * (HID / 4) + quad];
      acc.x += p.x; acc.y += p.y; acc.z += p.z; acc.w += p.w;
    }
    #pragma unroll
    for (int off = 8; off; off >>= 1) {
      acc.x += __shfl_down(acc.x, off, 16);
      acc.y += __shfl_down(acc.y, off, 16);
      acc.z += __shfl_down(acc.z, off, 16);
      acc.w += __shfl_down(acc.w, off, 16);
    }
    if (s == 0) {
      const float4 mm = reinterpret_cast<const float4*>(m)[quad];
      float4 gg = {acc.x * mm.x, acc.y * mm.y, acc.z * mm.z, acc.w * mm.w};
      reinterpret_cast<float4*>(g)[quad] = gg;
    }
  }

  grid.sync();

  // ---------- Phase 3: energies = enc @ g (64 MiB HBM, 16 rows/block) -------
  const float4* g4 = reinterpret_cast<const float4*>(g);
  #pragma unroll
  for (int rr = 0; rr < 4; ++rr) {
    const int row = bid * 16 + wave * 4 + rr;
    const float4* E = reinterpret_cast<const float4*>(enc + (size_t)row * HID);
    float acc = 0.f;
    #pragma unroll
    for (int i = lane; i < HID / 4; i += 64) {
      float4 e = E[i], gg = g4[i];
      acc += e.x * gg.x + e.y * gg.y + e.z * gg.z + e.w * gg.w;
    }
    #pragma unroll
    for (int off = 32; off; off >>= 1) acc += __shfl_down(acc, off, 64);
    if (lane == 0) energ[row] = acc;
  }

  grid.sync();

  // ---------- Phase 4: softmax — every block computes identical global ------
  // max/sum from L2-resident energ (bit-identical), writes its 16 outputs.
  float vals[32];
  float mx = -INFINITY;
  #pragma unroll
  for (int i = 0; i < 32; ++i) {
    vals[i] = energ[tid + i * NTHR];
    mx = fmaxf(mx, vals[i]);
  }
  #pragma unroll
  for (int off = 32; off; off >>= 1) mx = fmaxf(mx, __shfl_down(mx, off, 64));
  if (lane == 0) red[wave] = mx;
  __syncthreads();
  const float bm = fmaxf(fmaxf(red[0], red[1]), fmaxf(red[2], red[3]));

  float s = 0.f;
  #pragma unroll
  for (int i = 0; i < 32; ++i) s += expf(vals[i] - bm);
  #pragma unroll
  for (int off = 32; off; off >>= 1) s += __shfl_down(s, off, 64);
  if (lane == 0) red[4 + wave] = s;
  __syncthreads();
  const float inv = 1.f / (red[4] + red[5] + red[6] + red[7]);

  if (tid < 16) {
    const int row = bid * 16 + tid;
    out[row] = expf(energ[row] - bm) * inv;
  }
}

// ---------------------------------------------------------------------------
// Fallback path (proven round-1 kernels): memset + 3 dispatches, 43 us.
// ---------------------------------------------------------------------------
__global__ __launch_bounds__(256) void k_mv(const float* __restrict__ pool,
                                            const float* __restrict__ W_pq,
                                            const float* __restrict__ b_pq,
                                            const float* __restrict__ hidden,
                                            const float* __restrict__ W_qh,
                                            float* __restrict__ m,
                                            float* __restrict__ v) {
  const int bid  = blockIdx.x;
  const int wave = threadIdx.x >> 6;
  const int lane = threadIdx.x & 63;
  if (bid < 512) {
    const int row = bid * 4 + wave;
    const float4* Wrow = reinterpret_cast<const float4*>(W_pq + (size_t)row * HID);
    const float4* p4   = reinterpret_cast<const float4*>(pool);
    float acc = 0.f;
    #pragma unroll
    for (int i = lane; i < HID / 4; i += 64) {
      float4 w = Wrow[i], p = p4[i];
      acc += w.x * p.x + w.y * p.y + w.z * p.z + w.w * p.w;
    }
    #pragma unroll
    for (int off = 32; off; off >>= 1) acc += __shfl_down(acc, off, 64);
    if (lane == 0) m[row] = acc + b_pq[row];
  } else {
    const int b      = bid - 512;
    const int ctile  = b & 1;
    const int rchunk = b >> 1;
    const int c4     = ctile * 256 + threadIdx.x;
    const int r0     = rchunk * 16;
    float4 acc = {0.f, 0.f, 0.f, 0.f};
    #pragma unroll
    for (int r = r0; r < r0 + 16; ++r) {
      const float h  = hidden[r];
      const float4 w = reinterpret_cast<const float4*>(W_qh + (size_t)r * HID)[c4];
      acc.x += h * w.x; acc.y += h * w.y; acc.z += h * w.z; acc.w += h * w.w;
    }
    atomicAdd(&v[c4 * 4 + 0], acc.x);
    atomicAdd(&v[c4 * 4 + 1], acc.y);
    atomicAdd(&v[c4 * 4 + 2], acc.z);
    atomicAdd(&v[c4 * 4 + 3], acc.w);
  }
}

__global__ __launch_bounds__(256) void k_energy(const float* __restrict__ enc,
                                                const float* __restrict__ m,
                                                const float* __restrict__ v,
                                                float* __restrict__ energies) {
  const int wave = threadIdx.x >> 6;
  const int lane = threadIdx.x & 63;
  const int row  = blockIdx.x * 4 + wave;
  const float4* E  = reinterpret_cast<const float4*>(enc + (size_t)row * HID);
  const float4* m4 = reinterpret_cast<const float4*>(m);
  const float4* v4 = reinterpret_cast<const float4*>(v);
  float acc = 0.f;
  #pragma unroll
  for (int i = lane; i < HID / 4; i += 64) {
    float4 e = E[i], a = m4[i], b = v4[i];
    acc += e.x * a.x * b.x + e.y * a.y * b.y + e.z * a.z * b.z + e.w * a.w * b.w;
  }
  #pragma unroll
  for (int off = 32; off; off >>= 1) acc += __shfl_down(acc, off, 64);
  if (lane == 0) energies[row] = acc;
}

__global__ __launch_bounds__(1024) void k_softmax(const float* __restrict__ e,
                                                  float* __restrict__ out) {
  __shared__ float red[16];
  const int tid  = threadIdx.x;
  const int wave = tid >> 6;
  const int lane = tid & 63;
  float vals[8];
  float mx = -INFINITY;
  #pragma unroll
  for (int i = 0; i < 8; ++i) {
    vals[i] = e[tid + i * 1024];
    mx = fmaxf(mx, vals[i]);
  }
  #pragma unroll
  for (int off = 32; off; off >>= 1) mx = fmaxf(mx, __shfl_down(mx, off, 64));
  if (lane == 0) red[wave] = mx;
  __syncthreads();
  if (tid < 64) {
    float t = (tid < 16) ? red[tid] : -INFINITY;
    #pragma unroll
    for (int off = 8; off; off >>= 1) t = fmaxf(t, __shfl_down(t, off, 64));
    if (tid == 0) red[0] = t;
  }
  __syncthreads();
  mx = red[0];
  __syncthreads();
  float s = 0.f;
  #pragma unroll
  for (int i = 0; i < 8; ++i) {
    vals[i] = expf(vals[i] - mx);
    s += vals[i];
  }
  #pragma unroll
  for (int off = 32; off; off >>= 1) s += __shfl_down(s, off, 64);
  if (lane == 0) red[wave] = s;
  __syncthreads();
  if (tid < 64) {
    float t = (tid < 16) ? red[tid] : 0.f;
    #pragma unroll
    for (int off = 8; off; off >>= 1) t += __shfl_down(t, off, 64);
    if (tid == 0) red[0] = t;
  }
  __syncthreads();
  const float inv = 1.f / red[0];
  #pragma unroll
  for (int i = 0; i < 8; ++i) out[tid + i * 1024] = vals[i] * inv;
}

// ---------------------------------------------------------------------------
extern "C" void kernel_launch(void* const* d_in, const int* in_sizes, int n_in,
                              void* d_out, int out_size, void* d_ws, size_t ws_size,
                              hipStream_t stream) {
  const float* hidden = (const float*)d_in[0];  // (1, 2048)
  const float* enc    = (const float*)d_in[1];  // (8192, 2048)
  const float* pool   = (const float*)d_in[2];  // (1, 2048)
  const float* W_pq   = (const float*)d_in[3];  // (2048, 2048)
  const float* b_pq   = (const float*)d_in[4];  // (2048,)
  const float* W_qh   = (const float*)d_in[5];  // (2048, 2048)
  // d_in[6] = b_qh — uniform shift, cancels in softmax.

  float* out = (float*)d_out;
  float* ws  = (float*)d_ws;

  const size_t needed = (size_t)(2 * HID + SEQ + NCHUNK * HID) * sizeof(float);
  if (ws_size >= needed) {
    void* args[] = {(void*)&hidden, (void*)&enc, (void*)&pool, (void*)&W_pq,
                    (void*)&b_pq,   (void*)&W_qh, (void*)&out,  (void*)&ws};
    hipError_t err = hipLaunchCooperativeKernel((void*)k_fused, dim3(NBLK),
                                                dim3(NTHR), args, 0, stream);
    if (err == hipSuccess) return;
    (void)hipGetLastError();  // clear sticky error before fallback
  }

  // ---- fallback: proven 3-kernel path ----
  float* m        = ws;
  float* v        = ws + HID;
  float* energies = ws + 2 * HID;
  hipMemsetAsync(v, 0, HID * sizeof(float), stream);
  k_mv<<<dim3(512 + 256), dim3(256), 0, stream>>>(pool, W_pq, b_pq, hidden, W_qh, m, v);
  k_energy<<<dim3(SEQ / 4), dim3(256), 0, stream>>>(enc, m, v, energies);
  k_softmax<<<dim3(1), dim3(1024), 0, stream>>>(energies, out);
}

// Round 4
// 27.133 us; speedup vs baseline: 8.2646x; 8.2646x over previous
//
#include <hip/hip_runtime.h>
#include <math.h>

#define SEQ 8192
#define HID 2048
#define NC4 (HID / 4)   // 512 float4 per row
#define VCHUNKS 8       // v row-chunks of 256 rows

// Workspace (floats):
//   m     [0,     2048)
//   vpart [2048,  2048 + 8*2048)   : per-chunk partials of v = hidden @ W_qh
//   energ [18432, 18432 + 8192)

// ---------------------------------------------------------------------------
// K1: blocks 0..255  -> m[row] = W_pq[row,:].pool + b_pq[row]   (8 rows/block)
//     blocks 256..511-> vpart[rc][:] partials over 256-row chunks (no atomics)
// ---------------------------------------------------------------------------
__global__ __launch_bounds__(256) void k1(const float* __restrict__ pool,
                                          const float* __restrict__ W_pq,
                                          const float* __restrict__ b_pq,
                                          const float* __restrict__ hidden,
                                          const float* __restrict__ W_qh,
                                          float* __restrict__ m,
                                          float* __restrict__ vpart) {
  const int tid  = threadIdx.x;
  const int wave = tid >> 6;
  const int lane = tid & 63;
  const int bid  = blockIdx.x;

  if (bid < 256) {
    const float4* p4 = reinterpret_cast<const float4*>(pool);
    #pragma unroll
    for (int rr = 0; rr < 2; ++rr) {
      const int row = bid * 8 + wave * 2 + rr;
      const float4* Wrow = reinterpret_cast<const float4*>(W_pq + (size_t)row * HID);
      float acc = 0.f;
      #pragma unroll
      for (int i = lane; i < NC4; i += 64) {
        float4 w = Wrow[i], p = p4[i];
        acc += w.x * p.x + w.y * p.y + w.z * p.z + w.w * p.w;
      }
      #pragma unroll
      for (int off = 32; off; off >>= 1) acc += __shfl_down(acc, off, 64);
      if (lane == 0) m[row] = acc + b_pq[row];
    }
  } else {
    // unit u: rc = row-chunk (8 x 256 rows), ct = col-tile (32 x 16 float4)
    __shared__ float4 part[256];
    const int u  = bid - 256;
    const int ct = u & 31;
    const int rc = u >> 5;
    const int c4 = ct * 16 + (tid & 15);
    const int r0 = rc * 256 + (tid >> 4) * 16;
    float4 acc = {0.f, 0.f, 0.f, 0.f};
    #pragma unroll
    for (int i = 0; i < 16; ++i) {
      const int r = r0 + i;
      const float h  = hidden[r];
      const float4 w = reinterpret_cast<const float4*>(W_qh + (size_t)r * HID)[c4];
      acc.x += h * w.x; acc.y += h * w.y; acc.z += h * w.z; acc.w += h * w.w;
    }
    part[tid] = acc;
    __syncthreads();
    if (tid < 16) {
      float4 s = part[tid];
      #pragma unroll
      for (int k = 1; k < 16; ++k) {
        float4 p = part[k * 16 + tid];
        s.x += p.x; s.y += p.y; s.z += p.z; s.w += p.w;
      }
      reinterpret_cast<float4*>(vpart)[rc * NC4 + ct * 16 + tid] = s;
    }
  }
}

// ---------------------------------------------------------------------------
// K2: per block — reduce vpart (8 chunks) * m -> g in LDS, then 16 energy rows
// ---------------------------------------------------------------------------
__global__ __launch_bounds__(256) void k2(const float* __restrict__ enc,
                                          const float* __restrict__ m,
                                          const float* __restrict__ vpart,
                                          float* __restrict__ energ) {
  __shared__ float4 gl[NC4];
  const int tid  = threadIdx.x;
  const int wave = tid >> 6;
  const int lane = tid & 63;
  const int bid  = blockIdx.x;

  const float4* vp = reinterpret_cast<const float4*>(vpart);
  const float4* m4 = reinterpret_cast<const float4*>(m);
  #pragma unroll
  for (int j = 0; j < 2; ++j) {
    const int c = tid + j * 256;
    float4 a = vp[c];
    #pragma unroll
    for (int k = 1; k < VCHUNKS; ++k) {
      float4 p = vp[k * NC4 + c];
      a.x += p.x; a.y += p.y; a.z += p.z; a.w += p.w;
    }
    const float4 mm = m4[c];
    float4 g = {a.x * mm.x, a.y * mm.y, a.z * mm.z, a.w * mm.w};
    gl[c] = g;
  }
  __syncthreads();

  #pragma unroll
  for (int rr = 0; rr < 4; ++rr) {
    const int row = bid * 16 + wave * 4 + rr;
    const float4* E = reinterpret_cast<const float4*>(enc + (size_t)row * HID);
    float acc = 0.f;
    #pragma unroll
    for (int i = lane; i < NC4; i += 64) {
      float4 e = E[i], g = gl[i];
      acc += e.x * g.x + e.y * g.y + e.z * g.z + e.w * g.w;
    }
    #pragma unroll
    for (int off = 32; off; off >>= 1) acc += __shfl_down(acc, off, 64);
    if (lane == 0) energ[row] = acc;
  }
}

// ---------------------------------------------------------------------------
// K3: softmax — 32 blocks, each redundantly computes the identical global
// max/sum (bit-identical order), writes its own 256 outputs. No 1-CU tail.
// ---------------------------------------------------------------------------
__global__ __launch_bounds__(256) void k3(const float* __restrict__ e,
                                          float* __restrict__ out) {
  __shared__ float red[8];
  const int tid  = threadIdx.x;
  const int wave = tid >> 6;
  const int lane = tid & 63;
  const int bid  = blockIdx.x;

  float vals[32];
  float mx = -INFINITY;
  #pragma unroll
  for (int i = 0; i < 32; ++i) {
    vals[i] = e[tid + i * 256];
    mx = fmaxf(mx, vals[i]);
  }
  #pragma unroll
  for (int off = 32; off; off >>= 1) mx = fmaxf(mx, __shfl_down(mx, off, 64));
  if (lane == 0) red[wave] = mx;
  __syncthreads();
  const float bm = fmaxf(fmaxf(red[0], red[1]), fmaxf(red[2], red[3]));

  float s = 0.f;
  #pragma unroll
  for (int i = 0; i < 32; ++i) s += expf(vals[i] - bm);
  #pragma unroll
  for (int off = 32; off; off >>= 1) s += __shfl_down(s, off, 64);
  if (lane == 0) red[4 + wave] = s;
  __syncthreads();
  const float inv = 1.f / (red[4] + red[5] + red[6] + red[7]);

  const int row = bid * 256 + tid;
  out[row] = expf(e[row] - bm) * inv;
}

// ---------------------------------------------------------------------------
extern "C" void kernel_launch(void* const* d_in, const int* in_sizes, int n_in,
                              void* d_out, int out_size, void* d_ws, size_t ws_size,
                              hipStream_t stream) {
  const float* hidden = (const float*)d_in[0];  // (1, 2048)
  const float* enc    = (const float*)d_in[1];  // (8192, 2048)
  const float* pool   = (const float*)d_in[2];  // (1, 2048)
  const float* W_pq   = (const float*)d_in[3];  // (2048, 2048)
  const float* b_pq   = (const float*)d_in[4];  // (2048,)
  const float* W_qh   = (const float*)d_in[5];  // (2048, 2048)
  // d_in[6] = b_qh — uniform shift over seq, cancels in softmax.

  float* out   = (float*)d_out;
  float* ws    = (float*)d_ws;
  float* m     = ws;                       // 2048
  float* vpart = ws + HID;                 // 8 * 2048
  float* energ = ws + HID + VCHUNKS * HID; // 8192

  k1<<<dim3(512), dim3(256), 0, stream>>>(pool, W_pq, b_pq, hidden, W_qh, m, vpart);
  k2<<<dim3(512), dim3(256), 0, stream>>>(enc, m, vpart, energ);
  k3<<<dim3(32), dim3(256), 0, stream>>>(energ, out);
}